// Round 1
// baseline (340.650 us; speedup 1.0000x reference)
//
#include <hip/hip_runtime.h>
#include <hip/hip_bf16.h>
#include <math.h>

// Problem sizes
#define B_SZ 16
#define L_SZ 2048
#define H_SZ 1024
#define M_TOT (B_SZ * L_SZ)   // 32768 rows
#define N_TOT H_SZ            // 1024 outputs
#define KD (2 * H_SZ)         // 2048 concat K (key | query)
#define BM 128
#define BN 128
#define BK 32
#define NBN (N_TOT / BN)      // 8 column blocks
#define LC 16
#define LCHUNK (L_SZ / LC)    // 128

typedef short short8 __attribute__((ext_vector_type(8)));
typedef float f32x4 __attribute__((ext_vector_type(4)));

static __device__ __forceinline__ unsigned short f2bf(float f) {
    unsigned int u = __builtin_bit_cast(unsigned int, f);
    u += 0x7FFFu + ((u >> 16) & 1u);   // round-to-nearest-even
    return (unsigned short)(u >> 16);
}

static __device__ __forceinline__ short8 pack8(float4 x, float4 y) {
    short8 r;
    r[0] = (short)f2bf(x.x); r[1] = (short)f2bf(x.y);
    r[2] = (short)f2bf(x.z); r[3] = (short)f2bf(x.w);
    r[4] = (short)f2bf(y.x); r[5] = (short)f2bf(y.y);
    r[6] = (short)f2bf(y.z); r[7] = (short)f2bf(y.w);
    return r;
}

// ---------------------------------------------------------------------------
// Kernel 1: convert Wk|Wq (fp32 [1024][1024] each) -> Wb bf16 [1024][2048]
// ---------------------------------------------------------------------------
__global__ __launch_bounds__(256) void conv_w(
    const float* __restrict__ Wq, const float* __restrict__ Wk,
    unsigned short* __restrict__ Wb)
{
    int idx = blockIdx.x * 256 + threadIdx.x;   // 262144 threads, 8 elems each
    int e0 = idx * 8;
    int o  = e0 >> 11;          // output row
    int kk = e0 & 2047;         // concat-k
    const float* src = (kk < H_SZ) ? (Wk + (size_t)o * H_SZ + kk)
                                   : (Wq + (size_t)o * H_SZ + (kk - H_SZ));
    float4 x = ((const float4*)src)[0];
    float4 y = ((const float4*)src)[1];
    *(short8*)(Wb + e0) = pack8(x, y);
}

// ---------------------------------------------------------------------------
// Kernel 2: fused score GEMM.
// z[row][o] = sum_k ([key|query][row][k] * Wb[o][k]) ;
// spart[row][bn] = sum_{o in col-tile bn} w_score[o]*tanh(z+bias[o])
// 128x128 tile, 4 waves (2x2), 4x4 16x16x32 bf16 MFMA frags per wave.
// ---------------------------------------------------------------------------
__global__ __launch_bounds__(256, 2) void score_gemm(
    const float* __restrict__ Aq,            // query [M][1024] fp32
    const float* __restrict__ Ak,            // key_t [M][1024] fp32
    const unsigned short* __restrict__ Wb,   // [1024][2048] bf16
    const float* __restrict__ bias,
    const float* __restrict__ wscore,
    float* __restrict__ spart)               // [M][NBN]
{
    __shared__ unsigned short As[BM * BK];   // 8 KB
    __shared__ unsigned short Bs[BN * BK];   // 8 KB
    __shared__ float part[2][BM];            // 1 KB

    const int t    = threadIdx.x;
    const int bn   = blockIdx.x;             // col tile (fastest -> A reuse in L2/L3)
    const int bm   = blockIdx.y;             // row tile
    const int lane = t & 63;
    const int wid  = t >> 6;
    const int wr   = wid >> 1;               // wave row (0..1), 64 rows each
    const int wc   = wid & 1;                // wave col (0..1), 64 cols each

    const int r0g = bm * BM;
    const int c0g = bn * BN;

    // staging assignment: thread t covers rows (t>>2) and (t>>2)+64, koff (t&3)*8
    const int srow  = t >> 2;
    const int skoff = (t & 3) * 8;

    const int fr = lane & 15;                // fragment row/col within 16
    const int fg = lane >> 4;                // k-group (0..3)
    const int fk = fg * 8;

    f32x4 acc[4][4] = {};

    for (int kt = 0; kt < KD / BK; ++kt) {
        const int k0 = kt * BK;
        // ---- load A tile (fp32 source: key for k<1024, query after) ----
        const float* srcA = (k0 < H_SZ) ? (Ak + k0 + skoff)
                                        : (Aq + (k0 - H_SZ) + skoff);
        float4 a0 = *(const float4*)(srcA + (size_t)(r0g + srow) * H_SZ);
        float4 a1 = *(const float4*)(srcA + (size_t)(r0g + srow) * H_SZ + 4);
        float4 a2 = *(const float4*)(srcA + (size_t)(r0g + srow + 64) * H_SZ);
        float4 a3 = *(const float4*)(srcA + (size_t)(r0g + srow + 64) * H_SZ + 4);
        // ---- load B tile (bf16 source) ----
        short8 b0 = *(const short8*)(Wb + (size_t)(c0g + srow) * KD + k0 + skoff);
        short8 b1 = *(const short8*)(Wb + (size_t)(c0g + srow + 64) * KD + k0 + skoff);

        __syncthreads();   // previous iteration's LDS reads complete
        *(short8*)(As + srow * BK + skoff)        = pack8(a0, a1);
        *(short8*)(As + (srow + 64) * BK + skoff) = pack8(a2, a3);
        *(short8*)(Bs + srow * BK + skoff)        = b0;
        *(short8*)(Bs + (srow + 64) * BK + skoff) = b1;
        __syncthreads();   // tile ready

        short8 af[4], bf[4];
        #pragma unroll
        for (int m = 0; m < 4; ++m)
            af[m] = *(const short8*)(As + (wr * 64 + m * 16 + fr) * BK + fk);
        #pragma unroll
        for (int n = 0; n < 4; ++n)
            bf[n] = *(const short8*)(Bs + (wc * 64 + n * 16 + fr) * BK + fk);

        #pragma unroll
        for (int m = 0; m < 4; ++m)
            #pragma unroll
            for (int n = 0; n < 4; ++n)
                acc[m][n] = __builtin_amdgcn_mfma_f32_16x16x32_bf16(
                    af[m], bf[n], acc[m][n], 0, 0, 0);
    }

    // ---- fused epilogue: tanh + w_score reduction ----
    float wsv[4], bsv[4];
    #pragma unroll
    for (int n = 0; n < 4; ++n) {
        int cg = c0g + wc * 64 + n * 16 + fr;
        wsv[n] = wscore[cg];
        bsv[n] = bias[cg];
    }
    #pragma unroll
    for (int m = 0; m < 4; ++m) {
        #pragma unroll
        for (int r = 0; r < 4; ++r) {
            float s = 0.f;
            #pragma unroll
            for (int n = 0; n < 4; ++n)
                s += wsv[n] * tanhf(acc[m][n][r] + bsv[n]);
            // reduce across the 16 lanes sharing this row (C/D: col = lane&15)
            s += __shfl_xor(s, 1, 64);
            s += __shfl_xor(s, 2, 64);
            s += __shfl_xor(s, 4, 64);
            s += __shfl_xor(s, 8, 64);
            if (fr == 0)
                part[wc][wr * 64 + m * 16 + fg * 4 + r] = s;
        }
    }
    __syncthreads();
    if (t < BM) {
        float v = part[0][t] + part[1][t];
        spart[(size_t)(r0g + t) * NBN + bn] = v;
    }
}

// ---------------------------------------------------------------------------
// Kernel 3: per-batch softmax over L (sums the 8 partials in fixed order)
// ---------------------------------------------------------------------------
__global__ __launch_bounds__(256) void softmax_k(
    const float* __restrict__ spart,
    float* __restrict__ attn)                // d_out + 16384
{
    __shared__ float sc[L_SZ];
    __shared__ float red[8];
    const int b = blockIdx.x, t = threadIdx.x;
    const int lane = t & 63, wid = t >> 6;

    float lmax = -1e30f;
    #pragma unroll
    for (int i = 0; i < 8; ++i) {
        int l = t + i * 256;
        const float* p = spart + ((size_t)b * L_SZ + l) * NBN;
        float4 u = ((const float4*)p)[0];
        float4 v = ((const float4*)p)[1];
        float s = ((u.x + u.y) + (u.z + u.w)) + ((v.x + v.y) + (v.z + v.w));
        sc[l] = s;
        lmax = fmaxf(lmax, s);
    }
    #pragma unroll
    for (int off = 32; off; off >>= 1) lmax = fmaxf(lmax, __shfl_xor(lmax, off, 64));
    if (lane == 0) red[wid] = lmax;
    __syncthreads();
    float bmax = fmaxf(fmaxf(red[0], red[1]), fmaxf(red[2], red[3]));

    float lsum = 0.f;
    #pragma unroll
    for (int i = 0; i < 8; ++i) {
        int l = t + i * 256;
        float e = expf(sc[l] - bmax);
        sc[l] = e;
        lsum += e;
    }
    #pragma unroll
    for (int off = 32; off; off >>= 1) lsum += __shfl_xor(lsum, off, 64);
    if (lane == 0) red[4 + wid] = lsum;
    __syncthreads();
    float inv = 1.f / (((red[4] + red[5]) + (red[6] + red[7])));

    #pragma unroll
    for (int i = 0; i < 8; ++i) {
        int l = t + i * 256;
        attn[(size_t)b * L_SZ + l] = sc[l] * inv;
    }
}

// ---------------------------------------------------------------------------
// Kernel 4: context partials  cpart[b][lc][h] = sum_{l in chunk} attn*V
// ---------------------------------------------------------------------------
__global__ __launch_bounds__(256) void ctx_part_k(
    const float* __restrict__ attn, const float* __restrict__ value,
    float* __restrict__ cpart)               // [B][LC][H]
{
    const int bid = blockIdx.x;              // B*4*LC = 1024 blocks
    const int b   = bid >> 6;
    const int rem = bid & 63;
    const int hc  = rem >> 4;                // 0..3
    const int lc  = rem & 15;                // 0..15
    const int h   = hc * 256 + threadIdx.x;

    const float* ap = attn + (size_t)b * L_SZ + lc * LCHUNK;
    const float* vp = value + ((size_t)b * L_SZ + lc * LCHUNK) * H_SZ + h;
    float acc = 0.f;
    #pragma unroll 4
    for (int l = 0; l < LCHUNK; ++l)
        acc += ap[l] * vp[(size_t)l * H_SZ];
    cpart[((size_t)(b * LC + lc)) * H_SZ + h] = acc;
}

// ---------------------------------------------------------------------------
// Kernel 5: reduce context partials -> d_out[0:16384]
// ---------------------------------------------------------------------------
__global__ __launch_bounds__(256) void ctx_reduce_k(
    const float* __restrict__ cpart, float* __restrict__ ctx)
{
    const int idx = blockIdx.x * 256 + threadIdx.x;  // 16384
    const int b = idx >> 10, h = idx & 1023;
    float s = 0.f;
    #pragma unroll
    for (int lc = 0; lc < LC; ++lc)
        s += cpart[((size_t)(b * LC + lc)) * H_SZ + h];
    ctx[idx] = s;
}

// ---------------------------------------------------------------------------
extern "C" void kernel_launch(void* const* d_in, const int* in_sizes, int n_in,
                              void* d_out, int out_size, void* d_ws, size_t ws_size,
                              hipStream_t stream) {
    const float* query  = (const float*)d_in[0];
    const float* key_t  = (const float*)d_in[1];
    const float* value  = (const float*)d_in[2];
    const float* Wq     = (const float*)d_in[3];
    const float* Wk     = (const float*)d_in[4];
    const float* bias   = (const float*)d_in[5];
    const float* wscore = (const float*)d_in[6];

    float* out      = (float*)d_out;
    float* ctx_out  = out;                    // [16][1024] context
    float* attn_out = out + B_SZ * H_SZ;      // [16][2048] attn

    char* ws = (char*)d_ws;
    unsigned short* Wb = (unsigned short*)ws;                    // 4 MB bf16 weights
    float* spart = (float*)(ws + 4u * 1024u * 1024u);            // 1 MB score partials
    float* cpart = (float*)(ws + 5u * 1024u * 1024u);            // 1 MB ctx partials

    conv_w<<<1024, 256, 0, stream>>>(Wq, Wk, Wb);

    dim3 g(NBN, M_TOT / BM);   // col-tiles fastest: 8 blocks share one A-tile
    score_gemm<<<g, 256, 0, stream>>>(query, key_t, Wb, bias, wscore, spart);

    softmax_k<<<B_SZ, 256, 0, stream>>>(spart, attn_out);

    ctx_part_k<<<B_SZ * 4 * LC, 256, 0, stream>>>(attn_out, value, cpart);
    ctx_reduce_k<<<(B_SZ * H_SZ) / 256, 256, 0, stream>>>(cpart, ctx_out);
}

// Round 2
// 275.670 us; speedup vs baseline: 1.2357x; 1.2357x over previous
//
#include <hip/hip_runtime.h>
#include <hip/hip_bf16.h>
#include <math.h>

// Problem sizes
#define B_SZ 16
#define L_SZ 2048
#define H_SZ 1024
#define M_TOT (B_SZ * L_SZ)   // 32768 rows
#define N_TOT H_SZ            // 1024 outputs
#define KD (2 * H_SZ)         // 2048 concat K (key | query)
#define BM 128
#define BN 128
#define BK 32
#define NBN (N_TOT / BN)      // 8 column blocks
#define NBM (M_TOT / BM)      // 256 row blocks
#define LC 16
#define LCHUNK (L_SZ / LC)    // 128

typedef short short8 __attribute__((ext_vector_type(8)));
typedef float f32x4 __attribute__((ext_vector_type(4)));

// ws layout (fast path): Wb @0 (4MB), spart @4MB (1MB), cpart @5MB (1MB), Xb @6MB (128MB)
#define WS_FAST_BYTES (6ull * 1024 * 1024 + 2ull * (size_t)M_TOT * KD)

#define GL16(gp, lp)                                                        \
    __builtin_amdgcn_global_load_lds(                                       \
        (const __attribute__((address_space(1))) unsigned int*)(gp),        \
        (__attribute__((address_space(3))) unsigned int*)(lp), 16, 0, 0)

static __device__ __forceinline__ unsigned short f2bf(float f) {
    unsigned int u = __builtin_bit_cast(unsigned int, f);
    u += 0x7FFFu + ((u >> 16) & 1u);   // round-to-nearest-even
    return (unsigned short)(u >> 16);
}

static __device__ __forceinline__ short8 pack8(float4 x, float4 y) {
    short8 r;
    r[0] = (short)f2bf(x.x); r[1] = (short)f2bf(x.y);
    r[2] = (short)f2bf(x.z); r[3] = (short)f2bf(x.w);
    r[4] = (short)f2bf(y.x); r[5] = (short)f2bf(y.y);
    r[6] = (short)f2bf(y.z); r[7] = (short)f2bf(y.w);
    return r;
}

// ---------------------------------------------------------------------------
// Kernel 1 (fast path): concat + fp32->bf16.
// rows [0, 32768): Xb[row][0:1024]=key[row], [1024:2048]=query[row]
// rows [32768, 33792): Wb[o][0:1024]=Wk[o], [1024:2048]=Wq[o]
// ---------------------------------------------------------------------------
__global__ __launch_bounds__(256) void concat_bf16(
    const float* __restrict__ key, const float* __restrict__ query,
    const float* __restrict__ Wk, const float* __restrict__ Wq,
    unsigned short* __restrict__ Xb, unsigned short* __restrict__ Wb)
{
    long long e0 = ((long long)blockIdx.x * 256 + threadIdx.x) * 8;
    int row = (int)(e0 >> 11);
    int kk  = (int)(e0 & 2047);
    const float* a; const float* b; unsigned short* dst;
    if (row < M_TOT) { a = key; b = query; dst = Xb + e0; }
    else { row -= M_TOT; a = Wk; b = Wq; dst = Wb + (((long long)row << 11) | kk); }
    const float* src = (kk < H_SZ) ? (a + (size_t)row * H_SZ + kk)
                                   : (b + (size_t)row * H_SZ + (kk - H_SZ));
    float4 x = ((const float4*)src)[0];
    float4 y = ((const float4*)src)[1];
    *(short8*)dst = pack8(x, y);
}

// Fallback-path weight conversion only (4 MB Wb)
__global__ __launch_bounds__(256) void conv_w(
    const float* __restrict__ Wq, const float* __restrict__ Wk,
    unsigned short* __restrict__ Wb)
{
    int idx = blockIdx.x * 256 + threadIdx.x;
    int e0 = idx * 8;
    int o  = e0 >> 11;
    int kk = e0 & 2047;
    const float* src = (kk < H_SZ) ? (Wk + (size_t)o * H_SZ + kk)
                                   : (Wq + (size_t)o * H_SZ + (kk - H_SZ));
    float4 x = ((const float4*)src)[0];
    float4 y = ((const float4*)src)[1];
    *(short8*)(Wb + e0) = pack8(x, y);
}

// ---------------------------------------------------------------------------
// Kernel 2 (fast path): m97-structure score GEMM, all-bf16 inputs,
// global_load_lds width-16 staging, XCD-aware block remap, fused epilogue.
// ---------------------------------------------------------------------------
__global__ __launch_bounds__(256, 2) void score_gemm_fast(
    const unsigned short* __restrict__ Xb,   // [M][2048] bf16
    const unsigned short* __restrict__ Wb,   // [1024][2048] bf16
    const float* __restrict__ bias,
    const float* __restrict__ wscore,
    float* __restrict__ spart)               // [M][NBN]
{
    __shared__ unsigned short As[BM * BK];   // 8 KB, row-major [128][32]
    __shared__ unsigned short Bs[BN * BK];   // 8 KB
    __shared__ float part[2][BM];            // 1 KB

    const int t    = threadIdx.x;
    // XCD-aware remap: 2048 blocks = 8 xcd * 32 bm-chunk * 8 bn.
    // Blocks sharing an A row-tile get ids {i, i+8, .., i+56} -> same XCD.
    const int id  = blockIdx.x;
    const int xcd = id & 7;
    const int j   = id >> 3;          // 0..255
    const int bn  = j & 7;
    const int bm  = xcd * 32 + (j >> 3);

    const int lane = t & 63;
    const int wid  = t >> 6;
    const int wr   = wid >> 1;               // wave row (0..1)
    const int wc   = wid & 1;                // wave col (0..1)

    const int r0g = bm * BM;
    const int c0g = bn * BN;

    // staging: thread t covers row (t>>2) [+64 on 2nd issue], koff (t&3)*8
    const int srow  = t >> 2;                // 0..63
    const int skoff = (t & 3) * 8;

    const int fr = lane & 15;                // fragment row/col within 16
    const int fg = lane >> 4;                // k-group (0..3)
    const int fk = fg * 8;

    // wave-uniform LDS bases (global_load_lds: dest = base + lane*16B)
    unsigned short* aDst0 = &As[wid * 512];          // rows 0..63
    unsigned short* aDst1 = &As[2048 + wid * 512];   // rows 64..127
    unsigned short* bDst0 = &Bs[wid * 512];
    unsigned short* bDst1 = &Bs[2048 + wid * 512];

    const unsigned short* gA = Xb + (size_t)(r0g + srow) * KD + skoff;
    const unsigned short* gB = Wb + (size_t)(c0g + srow) * KD + skoff;

    f32x4 acc[4][4] = {};

    for (int kt = 0; kt < KD / BK; ++kt) {
        const int k0 = kt * BK;
        __syncthreads();   // previous iteration's LDS reads complete
        GL16(gA + k0, aDst0);
        GL16(gA + k0 + (size_t)64 * KD, aDst1);
        GL16(gB + k0, bDst0);
        GL16(gB + k0 + (size_t)64 * KD, bDst1);
        __syncthreads();   // (compiler drains vmcnt before barrier) tile ready

        short8 af[4], bf[4];
        #pragma unroll
        for (int m = 0; m < 4; ++m)
            af[m] = *(const short8*)(As + (wr * 64 + m * 16 + fr) * BK + fk);
        #pragma unroll
        for (int n = 0; n < 4; ++n)
            bf[n] = *(const short8*)(Bs + (wc * 64 + n * 16 + fr) * BK + fk);

        #pragma unroll
        for (int m = 0; m < 4; ++m)
            #pragma unroll
            for (int n = 0; n < 4; ++n)
                acc[m][n] = __builtin_amdgcn_mfma_f32_16x16x32_bf16(
                    af[m], bf[n], acc[m][n], 0, 0, 0);
    }

    // ---- fused epilogue: tanh + w_score reduction over this col-tile ----
    float wsv[4], bsv[4];
    #pragma unroll
    for (int n = 0; n < 4; ++n) {
        int cg = c0g + wc * 64 + n * 16 + fr;
        wsv[n] = wscore[cg];
        bsv[n] = bias[cg];
    }
    #pragma unroll
    for (int m = 0; m < 4; ++m) {
        #pragma unroll
        for (int r = 0; r < 4; ++r) {
            float s = 0.f;
            #pragma unroll
            for (int n = 0; n < 4; ++n)
                s += wsv[n] * tanhf(acc[m][n][r] + bsv[n]);
            s += __shfl_xor(s, 1, 64);
            s += __shfl_xor(s, 2, 64);
            s += __shfl_xor(s, 4, 64);
            s += __shfl_xor(s, 8, 64);
            if (fr == 0)
                part[wc][wr * 64 + m * 16 + fg * 4 + r] = s;
        }
    }
    __syncthreads();
    if (t < BM)
        spart[(size_t)(r0g + t) * NBN + bn] = part[0][t] + part[1][t];
}

// ---------------------------------------------------------------------------
// Fallback score GEMM (on-the-fly fp32->bf16 A staging) — used if ws too small
// ---------------------------------------------------------------------------
__global__ __launch_bounds__(256, 2) void score_gemm_fb(
    const float* __restrict__ Aq, const float* __restrict__ Ak,
    const unsigned short* __restrict__ Wb,
    const float* __restrict__ bias, const float* __restrict__ wscore,
    float* __restrict__ spart)
{
    __shared__ unsigned short As[BM * BK];
    __shared__ unsigned short Bs[BN * BK];
    __shared__ float part[2][BM];

    const int t    = threadIdx.x;
    const int bn   = blockIdx.x;
    const int bm   = blockIdx.y;
    const int lane = t & 63;
    const int wid  = t >> 6;
    const int wr   = wid >> 1;
    const int wc   = wid & 1;
    const int r0g = bm * BM;
    const int c0g = bn * BN;
    const int srow  = t >> 2;
    const int skoff = (t & 3) * 8;
    const int fr = lane & 15;
    const int fg = lane >> 4;
    const int fk = fg * 8;

    f32x4 acc[4][4] = {};

    for (int kt = 0; kt < KD / BK; ++kt) {
        const int k0 = kt * BK;
        const float* srcA = (k0 < H_SZ) ? (Ak + k0 + skoff)
                                        : (Aq + (k0 - H_SZ) + skoff);
        float4 a0 = *(const float4*)(srcA + (size_t)(r0g + srow) * H_SZ);
        float4 a1 = *(const float4*)(srcA + (size_t)(r0g + srow) * H_SZ + 4);
        float4 a2 = *(const float4*)(srcA + (size_t)(r0g + srow + 64) * H_SZ);
        float4 a3 = *(const float4*)(srcA + (size_t)(r0g + srow + 64) * H_SZ + 4);
        short8 b0 = *(const short8*)(Wb + (size_t)(c0g + srow) * KD + k0 + skoff);
        short8 b1 = *(const short8*)(Wb + (size_t)(c0g + srow + 64) * KD + k0 + skoff);

        __syncthreads();
        *(short8*)(As + srow * BK + skoff)        = pack8(a0, a1);
        *(short8*)(As + (srow + 64) * BK + skoff) = pack8(a2, a3);
        *(short8*)(Bs + srow * BK + skoff)        = b0;
        *(short8*)(Bs + (srow + 64) * BK + skoff) = b1;
        __syncthreads();

        short8 af[4], bf[4];
        #pragma unroll
        for (int m = 0; m < 4; ++m)
            af[m] = *(const short8*)(As + (wr * 64 + m * 16 + fr) * BK + fk);
        #pragma unroll
        for (int n = 0; n < 4; ++n)
            bf[n] = *(const short8*)(Bs + (wc * 64 + n * 16 + fr) * BK + fk);
        #pragma unroll
        for (int m = 0; m < 4; ++m)
            #pragma unroll
            for (int n = 0; n < 4; ++n)
                acc[m][n] = __builtin_amdgcn_mfma_f32_16x16x32_bf16(
                    af[m], bf[n], acc[m][n], 0, 0, 0);
    }

    float wsv[4], bsv[4];
    #pragma unroll
    for (int n = 0; n < 4; ++n) {
        int cg = c0g + wc * 64 + n * 16 + fr;
        wsv[n] = wscore[cg];
        bsv[n] = bias[cg];
    }
    #pragma unroll
    for (int m = 0; m < 4; ++m) {
        #pragma unroll
        for (int r = 0; r < 4; ++r) {
            float s = 0.f;
            #pragma unroll
            for (int n = 0; n < 4; ++n)
                s += wsv[n] * tanhf(acc[m][n][r] + bsv[n]);
            s += __shfl_xor(s, 1, 64);
            s += __shfl_xor(s, 2, 64);
            s += __shfl_xor(s, 4, 64);
            s += __shfl_xor(s, 8, 64);
            if (fr == 0)
                part[wc][wr * 64 + m * 16 + fg * 4 + r] = s;
        }
    }
    __syncthreads();
    if (t < BM)
        spart[(size_t)(r0g + t) * NBN + bn] = part[0][t] + part[1][t];
}

// ---------------------------------------------------------------------------
// Kernel 3: per-batch softmax over L (sums the 8 partials in fixed order)
// ---------------------------------------------------------------------------
__global__ __launch_bounds__(256) void softmax_k(
    const float* __restrict__ spart,
    float* __restrict__ attn)
{
    __shared__ float sc[L_SZ];
    __shared__ float red[8];
    const int b = blockIdx.x, t = threadIdx.x;
    const int lane = t & 63, wid = t >> 6;

    float lmax = -1e30f;
    #pragma unroll
    for (int i = 0; i < 8; ++i) {
        int l = t + i * 256;
        const float* p = spart + ((size_t)b * L_SZ + l) * NBN;
        float4 u = ((const float4*)p)[0];
        float4 v = ((const float4*)p)[1];
        float s = ((u.x + u.y) + (u.z + u.w)) + ((v.x + v.y) + (v.z + v.w));
        sc[l] = s;
        lmax = fmaxf(lmax, s);
    }
    #pragma unroll
    for (int off = 32; off; off >>= 1) lmax = fmaxf(lmax, __shfl_xor(lmax, off, 64));
    if (lane == 0) red[wid] = lmax;
    __syncthreads();
    float bmax = fmaxf(fmaxf(red[0], red[1]), fmaxf(red[2], red[3]));

    float lsum = 0.f;
    #pragma unroll
    for (int i = 0; i < 8; ++i) {
        int l = t + i * 256;
        float e = expf(sc[l] - bmax);
        sc[l] = e;
        lsum += e;
    }
    #pragma unroll
    for (int off = 32; off; off >>= 1) lsum += __shfl_xor(lsum, off, 64);
    if (lane == 0) red[4 + wid] = lsum;
    __syncthreads();
    float inv = 1.f / (((red[4] + red[5]) + (red[6] + red[7])));

    #pragma unroll
    for (int i = 0; i < 8; ++i) {
        int l = t + i * 256;
        attn[(size_t)b * L_SZ + l] = sc[l] * inv;
    }
}

// ---------------------------------------------------------------------------
// Kernel 4: context partials  cpart[b][lc][h] = sum_{l in chunk} attn*V
// ---------------------------------------------------------------------------
__global__ __launch_bounds__(256) void ctx_part_k(
    const float* __restrict__ attn, const float* __restrict__ value,
    float* __restrict__ cpart)
{
    const int bid = blockIdx.x;              // B*4*LC = 1024 blocks
    const int b   = bid >> 6;
    const int rem = bid & 63;
    const int hc  = rem >> 4;
    const int lc  = rem & 15;
    const int h   = hc * 256 + threadIdx.x;

    const float* ap = attn + (size_t)b * L_SZ + lc * LCHUNK;
    const float* vp = value + ((size_t)b * L_SZ + lc * LCHUNK) * H_SZ + h;
    float acc = 0.f;
    #pragma unroll 4
    for (int l = 0; l < LCHUNK; ++l)
        acc += ap[l] * vp[(size_t)l * H_SZ];
    cpart[((size_t)(b * LC + lc)) * H_SZ + h] = acc;
}

// ---------------------------------------------------------------------------
// Kernel 5: reduce context partials -> d_out[0:16384]
// ---------------------------------------------------------------------------
__global__ __launch_bounds__(256) void ctx_reduce_k(
    const float* __restrict__ cpart, float* __restrict__ ctx)
{
    const int idx = blockIdx.x * 256 + threadIdx.x;
    const int b = idx >> 10, h = idx & 1023;
    float s = 0.f;
    #pragma unroll
    for (int lc = 0; lc < LC; ++lc)
        s += cpart[((size_t)(b * LC + lc)) * H_SZ + h];
    ctx[idx] = s;
}

// ---------------------------------------------------------------------------
extern "C" void kernel_launch(void* const* d_in, const int* in_sizes, int n_in,
                              void* d_out, int out_size, void* d_ws, size_t ws_size,
                              hipStream_t stream) {
    const float* query  = (const float*)d_in[0];
    const float* key_t  = (const float*)d_in[1];
    const float* value  = (const float*)d_in[2];
    const float* Wq     = (const float*)d_in[3];
    const float* Wk     = (const float*)d_in[4];
    const float* bias   = (const float*)d_in[5];
    const float* wscore = (const float*)d_in[6];

    float* out      = (float*)d_out;
    float* ctx_out  = out;                    // [16][1024] context
    float* attn_out = out + B_SZ * H_SZ;      // [16][2048] attn

    char* ws = (char*)d_ws;
    unsigned short* Wb = (unsigned short*)ws;                    // 4 MB
    float* spart = (float*)(ws + 4ull * 1024 * 1024);            // 1 MB
    float* cpart = (float*)(ws + 5ull * 1024 * 1024);            // 1 MB
    unsigned short* Xb = (unsigned short*)(ws + 6ull * 1024 * 1024); // 128 MB

    if (ws_size >= WS_FAST_BYTES) {
        // (M_TOT + N_TOT) rows * 2048 elems / 8 per thread / 256 per block
        int nblk = ((M_TOT + N_TOT) * KD / 8) / 256;             // 33792
        concat_bf16<<<nblk, 256, 0, stream>>>(key_t, query, Wk, Wq, Xb, Wb);
        score_gemm_fast<<<NBN * NBM, 256, 0, stream>>>(Xb, Wb, bias, wscore, spart);
    } else {
        conv_w<<<1024, 256, 0, stream>>>(Wq, Wk, Wb);
        dim3 g(NBN, NBM);
        score_gemm_fb<<<g, 256, 0, stream>>>(query, key_t, Wb, bias, wscore, spart);
    }

    softmax_k<<<B_SZ, 256, 0, stream>>>(spart, attn_out);
    ctx_part_k<<<B_SZ * 4 * LC, 256, 0, stream>>>(attn_out, value, cpart);
    ctx_reduce_k<<<(B_SZ * H_SZ) / 256, 256, 0, stream>>>(cpart, ctx_out);
}

// Round 3
// 241.831 us; speedup vs baseline: 1.4086x; 1.1399x over previous
//
#include <hip/hip_runtime.h>
#include <hip/hip_bf16.h>
#include <math.h>

// Problem sizes
#define B_SZ 16
#define L_SZ 2048
#define H_SZ 1024
#define M_TOT (B_SZ * L_SZ)   // 32768 rows
#define N_TOT H_SZ            // 1024 outputs
#define KD (2 * H_SZ)         // 2048 concat K (key | query)
#define LC 16
#define LCHUNK (L_SZ / LC)    // 128

// 8-phase GEMM geometry (256^2 template)
#define BM2 256
#define BN2 256
#define BK2 64
#define NT2 (KD / BK2)        // 32 K-tiles
#define NBN2 (N_TOT / BN2)    // 4 col blocks
#define NBM2 (M_TOT / BM2)    // 128 row blocks

typedef short short8 __attribute__((ext_vector_type(8)));
typedef float f32x4 __attribute__((ext_vector_type(4)));

// ws layout: Wb @0 (4MB), spart @4MB (512KB), cpart @5MB (1MB), Xb @6MB (128MB)
#define WS_FAST_BYTES (6ull * 1024 * 1024 + 2ull * (size_t)M_TOT * KD)

#define GL16(gp, lp)                                                        \
    __builtin_amdgcn_global_load_lds(                                       \
        (const __attribute__((address_space(1))) unsigned int*)(gp),        \
        (__attribute__((address_space(3))) unsigned int*)(lp), 16, 0, 0)

#define BARRIER() __builtin_amdgcn_s_barrier()
#define LGKM0()  do { asm volatile("s_waitcnt lgkmcnt(0)" ::: "memory");    \
                      __builtin_amdgcn_sched_barrier(0); } while (0)
#define VMCNT4() do { asm volatile("s_waitcnt vmcnt(4)" ::: "memory");      \
                      __builtin_amdgcn_sched_barrier(0); } while (0)
#define VMCNT0() do { asm volatile("s_waitcnt vmcnt(0)" ::: "memory");      \
                      __builtin_amdgcn_sched_barrier(0); } while (0)

static __device__ __forceinline__ unsigned short f2bf(float f) {
    unsigned int u = __builtin_bit_cast(unsigned int, f);
    u += 0x7FFFu + ((u >> 16) & 1u);   // round-to-nearest-even
    return (unsigned short)(u >> 16);
}

static __device__ __forceinline__ short8 pack8(float4 x, float4 y) {
    short8 r;
    r[0] = (short)f2bf(x.x); r[1] = (short)f2bf(x.y);
    r[2] = (short)f2bf(x.z); r[3] = (short)f2bf(x.w);
    r[4] = (short)f2bf(y.x); r[5] = (short)f2bf(y.y);
    r[6] = (short)f2bf(y.z); r[7] = (short)f2bf(y.w);
    return r;
}

// ---------------------------------------------------------------------------
// Kernel 1: concat + fp32->bf16.
// rows [0, 32768): Xb[row][0:1024]=key[row], [1024:2048]=query[row]
// rows [32768, 33792): Wb[o][0:1024]=Wk[o], [1024:2048]=Wq[o]
// ---------------------------------------------------------------------------
__global__ __launch_bounds__(256) void concat_bf16(
    const float* __restrict__ key, const float* __restrict__ query,
    const float* __restrict__ Wk, const float* __restrict__ Wq,
    unsigned short* __restrict__ Xb, unsigned short* __restrict__ Wb)
{
    long long e0 = ((long long)blockIdx.x * 256 + threadIdx.x) * 8;
    int row = (int)(e0 >> 11);
    int kk  = (int)(e0 & 2047);
    const float* a; const float* b; unsigned short* dst;
    if (row < M_TOT) { a = key; b = query; dst = Xb + e0; }
    else { row -= M_TOT; a = Wk; b = Wq; dst = Wb + (((long long)row << 11) | kk); }
    const float* src = (kk < H_SZ) ? (a + (size_t)row * H_SZ + kk)
                                   : (b + (size_t)row * H_SZ + (kk - H_SZ));
    float4 x = ((const float4*)src)[0];
    float4 y = ((const float4*)src)[1];
    *(short8*)dst = pack8(x, y);
}

// ---------------------------------------------------------------------------
// Kernel 2: 256x256x64 8-phase score GEMM (HK template re-derived).
//   A = Xb [M][2048] bf16, B = Wb [1024][2048] bf16 (both row x K).
//   LDS: A [2buf][2 khalf][16 rsub][1024B] @0, B same @64KB. st_16x32 swizzle
//   (byte ^= 32 for rows 8-15 of each 16-row subtile) applied on BOTH sides:
//   pre-swizzled global source for global_load_lds + swizzled ds_read addr.
//   Phases per K-tile: (ks0,mh0)+LDB0 | (ks0,mh1) | (ks1,mh0)+LDB1 | (ks1,mh1).
//   Stage stream in tile u: ph1 A-Kh1(u+1)->buf^1, ph2 B-Kh1(u+1)->buf^1,
//   ph3 A-Kh0(u+2)->buf, ph4 B-Kh0(u+2)->buf.  vmcnt(4) at each tile boundary
//   => all 4 halves of tile u+1 landed before any wave reads them (then
//   barrier makes it a block-wide guarantee). Issue-safety: every stage
//   targets a region whose last readers finished before a barrier that
//   precedes the issue.
//   Fused epilogue: tanh + w_score partial reduction -> spart[M][4].
// ---------------------------------------------------------------------------
__global__ __launch_bounds__(512, 2) void score_gemm_8ph(
    const unsigned short* __restrict__ Xb,
    const unsigned short* __restrict__ Wb,
    const float* __restrict__ bias,
    const float* __restrict__ wscore,
    float* __restrict__ spart)               // [M][4]
{
    extern __shared__ char smem[];           // 128 KB dynamic
    char* Albase = smem;                     // A: 64 KB
    char* Blbase = smem + 65536;             // B: 64 KB

    const int t    = threadIdx.x;
    const int lane = t & 63;
    const int wid  = t >> 6;                 // 0..7
    const int wr   = wid >> 2;               // 0..1 (WARPS_M=2, 128 rows each)
    const int wc   = wid & 3;                // 0..3 (WARPS_N=4, 64 cols each)

    // XCD-aware remap: 512 blocks = 8 xcd * 16 bm * 4 bn (bn innermost)
    const int id  = blockIdx.x;
    const int xcd = id & 7;
    const int j   = id >> 3;                 // 0..63
    const int bn  = j & 3;
    const int bm  = xcd * 16 + (j >> 2);
    const int r0  = bm * BM2;
    const int c0  = bn * BN2;

    // ---- staging per-lane global offsets (pre-swizzled source) ----
    // one gload_lds wave-inst = one 16x32-elem subtile (1KB), lane l ->
    // row l>>2, col (l&3)*8 ^ (l>=32 ? 16 : 0)  [involution of st_16x32]
    const int srow = lane >> 2;
    const int scol = ((lane & 3) * 8) ^ ((lane >= 32) ? 16 : 0);
    // issue i stages subtile rsub = i*8 + wid of the half-tile
    const size_t gA0 = (size_t)(r0 + (wid)     * 16 + srow) * KD + scol;
    const size_t gA1 = (size_t)(r0 + (8 + wid) * 16 + srow) * KD + scol;
    const size_t gB0 = (size_t)(c0 + (wid)     * 16 + srow) * KD + scol;
    const size_t gB1 = (size_t)(c0 + (8 + wid) * 16 + srow) * KD + scol;

    // ---- frag ds_read addressing (swizzled) ----
    const int fr  = lane & 15;               // row within subtile / C-col
    const int fk8 = (lane >> 4) * 8;         // k-offset within 32-k step
    const int subbyte = (fr * 64 + fk8 * 2) ^ ((fr & 8) << 2);  // ^32 if fr>=8
    const char* aL = Albase + wr * 8192 + subbyte;   // + rsub*1024 immediates
    const char* bL = Blbase + wc * 4096 + subbyte;

#define STAGE_A(buf, khalf, kt_) do {                                        \
    int kpos = (((kt_) & 31) * 64) + (khalf) * 32;                           \
    GL16(Xb + gA0 + kpos, Albase + (((buf)*2 + (khalf))*16 + wid)*1024);     \
    GL16(Xb + gA1 + kpos, Albase + (((buf)*2 + (khalf))*16 + 8 + wid)*1024); \
} while (0)
#define STAGE_B(buf, khalf, kt_) do {                                        \
    int kpos = (((kt_) & 31) * 64) + (khalf) * 32;                           \
    GL16(Wb + gB0 + kpos, Blbase + (((buf)*2 + (khalf))*16 + wid)*1024);     \
    GL16(Wb + gB1 + kpos, Blbase + (((buf)*2 + (khalf))*16 + 8 + wid)*1024); \
} while (0)

    short8 a_f[4], b_f0[4], b_f1[4];
    f32x4 acc[8][4] = {};

#define LDA4(buf, ks, mh) do { _Pragma("unroll")                             \
    for (int m = 0; m < 4; ++m)                                              \
        a_f[m] = *(const short8*)(aL +                                       \
            (((buf)*2 + (ks))*16 + (mh)*4 + m) * 1024); } while (0)
#define LDB4(dst, buf, ks) do { _Pragma("unroll")                            \
    for (int n = 0; n < 4; ++n)                                              \
        dst[n] = *(const short8*)(bL +                                       \
            (((buf)*2 + (ks))*16 + n) * 1024); } while (0)
#define MM16(bff, mh) do {                                                   \
    __builtin_amdgcn_s_setprio(1);                                           \
    _Pragma("unroll")                                                        \
    for (int m = 0; m < 4; ++m) { _Pragma("unroll")                          \
        for (int n = 0; n < 4; ++n)                                          \
            acc[(mh)*4 + m][n] = __builtin_amdgcn_mfma_f32_16x16x32_bf16(    \
                a_f[m], bff[n], acc[(mh)*4 + m][n], 0, 0, 0); }              \
    __builtin_amdgcn_s_setprio(0); } while (0)

#define TILE(buf, u) do {                                                    \
    LDA4(buf, 0, 0); LDB4(b_f0, buf, 0); STAGE_A(1-(buf), 1, (u)+1);         \
    BARRIER(); LGKM0(); MM16(b_f0, 0); BARRIER();                            \
    LDA4(buf, 0, 1); STAGE_B(1-(buf), 1, (u)+1);                             \
    BARRIER(); LGKM0(); MM16(b_f0, 1); BARRIER();                            \
    LDA4(buf, 1, 0); LDB4(b_f1, buf, 1); STAGE_A(buf, 0, (u)+2);             \
    BARRIER(); LGKM0(); MM16(b_f1, 0); BARRIER();                            \
    LDA4(buf, 1, 1); STAGE_B(buf, 0, (u)+2);                                 \
    BARRIER(); LGKM0(); MM16(b_f1, 1); VMCNT4(); BARRIER();                  \
} while (0)

    // ---- prologue: tile0 complete + tile1 Kh0; tile0 landed, Kh0(1) in flight
    STAGE_A(0, 0, 0); STAGE_B(0, 0, 0);
    STAGE_A(0, 1, 0); STAGE_B(0, 1, 0);
    STAGE_A(1, 0, 1); STAGE_B(1, 0, 1);
    VMCNT4(); BARRIER();

    // ---- main loop: 32 K-tiles, unrolled x2 for static buffer index ----
    for (int it = 0; it < NT2; it += 2) {
        TILE(0, it);
        TILE(1, it + 1);
    }

    // drain stray wrapped prefetches before reusing LDS
    VMCNT0();
    __syncthreads();

    // ---- fused epilogue: tanh + w_score partial over this col-tile ----
    float* part = (float*)smem;              // [4][256]
    const int fg = lane >> 4;
    float wsv[4], bsv[4];
    #pragma unroll
    for (int n = 0; n < 4; ++n) {
        int cg = c0 + wc * 64 + n * 16 + fr;
        wsv[n] = wscore[cg];
        bsv[n] = bias[cg];
    }
    #pragma unroll
    for (int mm = 0; mm < 8; ++mm) {
        #pragma unroll
        for (int r = 0; r < 4; ++r) {
            float s = 0.f;
            #pragma unroll
            for (int n = 0; n < 4; ++n)
                s += wsv[n] * tanhf(acc[mm][n][r] + bsv[n]);
            s += __shfl_xor(s, 1, 64);
            s += __shfl_xor(s, 2, 64);
            s += __shfl_xor(s, 4, 64);
            s += __shfl_xor(s, 8, 64);
            if (fr == 0)
                part[wc * 256 + wr * 128 + mm * 16 + fg * 4 + r] = s;
        }
    }
    __syncthreads();
    if (t < 256) {
        float v = part[t] + part[256 + t] + part[512 + t] + part[768 + t];
        spart[(size_t)(r0 + t) * 4 + bn] = v;
    }

#undef STAGE_A
#undef STAGE_B
#undef LDA4
#undef LDB4
#undef MM16
#undef TILE
}

// ---------------------------------------------------------------------------
// Kernel 3: per-batch softmax over L (sums the 4 partials in fixed order)
// ---------------------------------------------------------------------------
__global__ __launch_bounds__(256) void softmax_k(
    const float* __restrict__ spart,         // [M][4]
    float* __restrict__ attn)
{
    __shared__ float sc[L_SZ];
    __shared__ float red[8];
    const int b = blockIdx.x, t = threadIdx.x;
    const int lane = t & 63, wid = t >> 6;

    float lmax = -1e30f;
    #pragma unroll
    for (int i = 0; i < 8; ++i) {
        int l = t + i * 256;
        float4 u = *(const float4*)(spart + ((size_t)b * L_SZ + l) * 4);
        float s = (u.x + u.y) + (u.z + u.w);
        sc[l] = s;
        lmax = fmaxf(lmax, s);
    }
    #pragma unroll
    for (int off = 32; off; off >>= 1) lmax = fmaxf(lmax, __shfl_xor(lmax, off, 64));
    if (lane == 0) red[wid] = lmax;
    __syncthreads();
    float bmax = fmaxf(fmaxf(red[0], red[1]), fmaxf(red[2], red[3]));

    float lsum = 0.f;
    #pragma unroll
    for (int i = 0; i < 8; ++i) {
        int l = t + i * 256;
        float e = expf(sc[l] - bmax);
        sc[l] = e;
        lsum += e;
    }
    #pragma unroll
    for (int off = 32; off; off >>= 1) lsum += __shfl_xor(lsum, off, 64);
    if (lane == 0) red[4 + wid] = lsum;
    __syncthreads();
    float inv = 1.f / (((red[4] + red[5]) + (red[6] + red[7])));

    #pragma unroll
    for (int i = 0; i < 8; ++i) {
        int l = t + i * 256;
        attn[(size_t)b * L_SZ + l] = sc[l] * inv;
    }
}

// ---------------------------------------------------------------------------
// Kernel 4: context partials  cpart[b][lc][h] = sum_{l in chunk} attn*V
// ---------------------------------------------------------------------------
__global__ __launch_bounds__(256) void ctx_part_k(
    const float* __restrict__ attn, const float* __restrict__ value,
    float* __restrict__ cpart)
{
    const int bid = blockIdx.x;              // B*4*LC = 1024 blocks
    const int b   = bid >> 6;
    const int rem = bid & 63;
    const int hc  = rem >> 4;
    const int lc  = rem & 15;
    const int h   = hc * 256 + threadIdx.x;

    const float* ap = attn + (size_t)b * L_SZ + lc * LCHUNK;
    const float* vp = value + ((size_t)b * L_SZ + lc * LCHUNK) * H_SZ + h;
    float acc = 0.f;
    #pragma unroll 4
    for (int l = 0; l < LCHUNK; ++l)
        acc += ap[l] * vp[(size_t)l * H_SZ];
    cpart[((size_t)(b * LC + lc)) * H_SZ + h] = acc;
}

// ---------------------------------------------------------------------------
// Kernel 5: reduce context partials -> d_out[0:16384]
// ---------------------------------------------------------------------------
__global__ __launch_bounds__(256) void ctx_reduce_k(
    const float* __restrict__ cpart, float* __restrict__ ctx)
{
    const int idx = blockIdx.x * 256 + threadIdx.x;
    const int b = idx >> 10, h = idx & 1023;
    float s = 0.f;
    #pragma unroll
    for (int lc = 0; lc < LC; ++lc)
        s += cpart[((size_t)(b * LC + lc)) * H_SZ + h];
    ctx[idx] = s;
}

// ---------------------------------------------------------------------------
extern "C" void kernel_launch(void* const* d_in, const int* in_sizes, int n_in,
                              void* d_out, int out_size, void* d_ws, size_t ws_size,
                              hipStream_t stream) {
    const float* query  = (const float*)d_in[0];
    const float* key_t  = (const float*)d_in[1];
    const float* value  = (const float*)d_in[2];
    const float* Wq     = (const float*)d_in[3];
    const float* Wk     = (const float*)d_in[4];
    const float* bias   = (const float*)d_in[5];
    const float* wscore = (const float*)d_in[6];

    float* out      = (float*)d_out;
    float* ctx_out  = out;                    // [16][1024] context
    float* attn_out = out + B_SZ * H_SZ;      // [16][2048] attn

    char* ws = (char*)d_ws;                   // ws_size verified >= 140MB (R1/R2 ran fast path)
    unsigned short* Wb = (unsigned short*)ws;                        // 4 MB
    float* spart = (float*)(ws + 4ull * 1024 * 1024);                // 512 KB [M][4]
    float* cpart = (float*)(ws + 5ull * 1024 * 1024);                // 1 MB
    unsigned short* Xb = (unsigned short*)(ws + 6ull * 1024 * 1024); // 128 MB

    // allow 128 KB dynamic LDS (idempotent; not a stream op)
    (void)hipFuncSetAttribute((const void*)score_gemm_8ph,
                              hipFuncAttributeMaxDynamicSharedMemorySize, 131072);

    int nblk = ((M_TOT + N_TOT) * KD / 8) / 256;                     // 33792
    concat_bf16<<<nblk, 256, 0, stream>>>(key_t, query, Wk, Wq, Xb, Wb);

    score_gemm_8ph<<<NBM2 * NBN2, 512, 131072, stream>>>(Xb, Wb, bias, wscore, spart);

    softmax_k<<<B_SZ, 256, 0, stream>>>(spart, attn_out);
    ctx_part_k<<<B_SZ * 4 * LC, 256, 0, stream>>>(attn_out, value, cpart);
    ctx_reduce_k<<<(B_SZ * H_SZ) / 256, 256, 0, stream>>>(cpart, ctx_out);
}

// Round 4
// 222.190 us; speedup vs baseline: 1.5331x; 1.0884x over previous
//
#include <hip/hip_runtime.h>
#include <hip/hip_bf16.h>
#include <math.h>

// Problem sizes
#define B_SZ 16
#define L_SZ 2048
#define H_SZ 1024
#define M_TOT (B_SZ * L_SZ)   // 32768 rows
#define N_TOT H_SZ            // 1024 outputs
#define KD (2 * H_SZ)         // 2048 concat K (key | query)
#define LC 16
#define LCHUNK (L_SZ / LC)    // 128

// 8-phase GEMM geometry (256^2 template)
#define BM2 256
#define BN2 256
#define BK2 64
#define NT2 (KD / BK2)        // 32 K-tiles
#define NBN2 (N_TOT / BN2)    // 4 col blocks
#define NBM2 (M_TOT / BM2)    // 128 row blocks

typedef short short8 __attribute__((ext_vector_type(8)));
typedef float f32x4 __attribute__((ext_vector_type(4)));

// ws layout: Wb @0 (4MB), spart @4MB (512KB), cpart @5MB (1MB), Xb @6MB (128MB)
#define WS_FAST_BYTES (6ull * 1024 * 1024 + 2ull * (size_t)M_TOT * KD)

#define GL16(gp, lp)                                                        \
    __builtin_amdgcn_global_load_lds(                                       \
        (const __attribute__((address_space(1))) unsigned int*)(gp),        \
        (__attribute__((address_space(3))) unsigned int*)(lp), 16, 0, 0)

#define BARRIER() __builtin_amdgcn_s_barrier()
// Plain asm waits — NO sched_barrier(0): our ds_reads are compiler-visible,
// so the compiler emits its own fine-grained lgkmcnt before dependent MFMAs;
// pinning the schedule (m141) cost −42% in learn_hip. "memory" clobber still
// keeps all memory ops (ds_read / gload_lds) ordered across these waits.
#define LGKM0()  asm volatile("s_waitcnt lgkmcnt(0)" ::: "memory")
#define VMCNT4() asm volatile("s_waitcnt vmcnt(4)" ::: "memory")
#define VMCNT0() asm volatile("s_waitcnt vmcnt(0)" ::: "memory")

static __device__ __forceinline__ unsigned short f2bf(float f) {
    unsigned int u = __builtin_bit_cast(unsigned int, f);
    u += 0x7FFFu + ((u >> 16) & 1u);   // round-to-nearest-even
    return (unsigned short)(u >> 16);
}

static __device__ __forceinline__ short8 pack8(float4 x, float4 y) {
    short8 r;
    r[0] = (short)f2bf(x.x); r[1] = (short)f2bf(x.y);
    r[2] = (short)f2bf(x.z); r[3] = (short)f2bf(x.w);
    r[4] = (short)f2bf(y.x); r[5] = (short)f2bf(y.y);
    r[6] = (short)f2bf(y.z); r[7] = (short)f2bf(y.w);
    return r;
}

// tanh(x) = 1 - 2/(e^{2x}+1); v_exp_f32 + v_rcp_f32, ~1e-6 abs err,
// exact saturation at +-1 (e->inf -> 1, e->0 -> -1).
static __device__ __forceinline__ float fast_tanh(float x) {
    float e = __expf(2.0f * x);
    return 1.0f - 2.0f * __builtin_amdgcn_rcpf(e + 1.0f);
}

// ---------------------------------------------------------------------------
// Kernel 1: concat + fp32->bf16.
// rows [0, 32768): Xb[row][0:1024]=key[row], [1024:2048]=query[row]
// rows [32768, 33792): Wb[o][0:1024]=Wk[o], [1024:2048]=Wq[o]
// ---------------------------------------------------------------------------
__global__ __launch_bounds__(256) void concat_bf16(
    const float* __restrict__ key, const float* __restrict__ query,
    const float* __restrict__ Wk, const float* __restrict__ Wq,
    unsigned short* __restrict__ Xb, unsigned short* __restrict__ Wb)
{
    long long e0 = ((long long)blockIdx.x * 256 + threadIdx.x) * 8;
    int row = (int)(e0 >> 11);
    int kk  = (int)(e0 & 2047);
    const float* a; const float* b; unsigned short* dst;
    if (row < M_TOT) { a = key; b = query; dst = Xb + e0; }
    else { row -= M_TOT; a = Wk; b = Wq; dst = Wb + (((long long)row << 11) | kk); }
    const float* src = (kk < H_SZ) ? (a + (size_t)row * H_SZ + kk)
                                   : (b + (size_t)row * H_SZ + (kk - H_SZ));
    float4 x = ((const float4*)src)[0];
    float4 y = ((const float4*)src)[1];
    *(short8*)dst = pack8(x, y);
}

// ---------------------------------------------------------------------------
// Kernel 2: 256x256x64 8-phase score GEMM (HK template re-derived).
//   A = Xb [M][2048] bf16, B = Wb [1024][2048] bf16 (both row x K).
//   LDS: A [2buf][2 khalf][16 rsub][1024B] @0, B same @64KB. st_16x32 swizzle
//   applied both-sides (pre-swizzled global source + swizzled ds_read addr).
//   Phases per K-tile: (ks0,mh0)+LDB0 | (ks0,mh1) | (ks1,mh0)+LDB1 | (ks1,mh1).
//   Stage stream in tile u: ph1 A-Kh1(u+1)->buf^1, ph2 B-Kh1(u+1)->buf^1,
//   ph3 A-Kh0(u+2)->buf, ph4 B-Kh0(u+2)->buf.  vmcnt(4) at each tile boundary
//   => all 4 halves of tile u+1 landed before any wave reads them.
//   Fused epilogue: tanh + w_score partial reduction -> spart[M][4].
// ---------------------------------------------------------------------------
__global__ __launch_bounds__(512, 2) void score_gemm_8ph(
    const unsigned short* __restrict__ Xb,
    const unsigned short* __restrict__ Wb,
    const float* __restrict__ bias,
    const float* __restrict__ wscore,
    float* __restrict__ spart)               // [M][4]
{
    extern __shared__ char smem[];           // 128 KB dynamic
    char* Albase = smem;                     // A: 64 KB
    char* Blbase = smem + 65536;             // B: 64 KB

    const int t    = threadIdx.x;
    const int lane = t & 63;
    const int wid  = t >> 6;                 // 0..7
    const int wr   = wid >> 2;               // 0..1 (WARPS_M=2, 128 rows each)
    const int wc   = wid & 3;                // 0..3 (WARPS_N=4, 64 cols each)

    // XCD-aware remap: 512 blocks = 8 xcd * 16 bm * 4 bn (bn innermost)
    const int id  = blockIdx.x;
    const int xcd = id & 7;
    const int j   = id >> 3;                 // 0..63
    const int bn  = j & 3;
    const int bm  = xcd * 16 + (j >> 2);
    const int r0  = bm * BM2;
    const int c0  = bn * BN2;

    // ---- staging per-lane global offsets (pre-swizzled source) ----
    // one gload_lds wave-inst = one 16x32-elem subtile (1KB), lane l ->
    // row l>>2, col (l&3)*8 ^ (l>=32 ? 16 : 0)  [involution of st_16x32]
    const int srow = lane >> 2;
    const int scol = ((lane & 3) * 8) ^ ((lane >= 32) ? 16 : 0);
    // issue i stages subtile rsub = i*8 + wid of the half-tile
    const size_t gA0 = (size_t)(r0 + (wid)     * 16 + srow) * KD + scol;
    const size_t gA1 = (size_t)(r0 + (8 + wid) * 16 + srow) * KD + scol;
    const size_t gB0 = (size_t)(c0 + (wid)     * 16 + srow) * KD + scol;
    const size_t gB1 = (size_t)(c0 + (8 + wid) * 16 + srow) * KD + scol;

    // ---- frag ds_read addressing (swizzled) ----
    const int fr  = lane & 15;               // row within subtile / C-col
    const int fk8 = (lane >> 4) * 8;         // k-offset within 32-k step
    const int subbyte = (fr * 64 + fk8 * 2) ^ ((fr & 8) << 2);  // ^32 if fr>=8
    const char* aL = Albase + wr * 8192 + subbyte;   // + rsub*1024 immediates
    const char* bL = Blbase + wc * 4096 + subbyte;

#define STAGE_A(buf, khalf, kt_) do {                                        \
    int kpos = (((kt_) & 31) * 64) + (khalf) * 32;                           \
    GL16(Xb + gA0 + kpos, Albase + (((buf)*2 + (khalf))*16 + wid)*1024);     \
    GL16(Xb + gA1 + kpos, Albase + (((buf)*2 + (khalf))*16 + 8 + wid)*1024); \
} while (0)
#define STAGE_B(buf, khalf, kt_) do {                                        \
    int kpos = (((kt_) & 31) * 64) + (khalf) * 32;                           \
    GL16(Wb + gB0 + kpos, Blbase + (((buf)*2 + (khalf))*16 + wid)*1024);     \
    GL16(Wb + gB1 + kpos, Blbase + (((buf)*2 + (khalf))*16 + 8 + wid)*1024); \
} while (0)

    short8 a_f[4], b_f0[4], b_f1[4];
    f32x4 acc[8][4] = {};

#define LDA4(buf, ks, mh) do { _Pragma("unroll")                             \
    for (int m = 0; m < 4; ++m)                                              \
        a_f[m] = *(const short8*)(aL +                                       \
            (((buf)*2 + (ks))*16 + (mh)*4 + m) * 1024); } while (0)
#define LDB4(dst, buf, ks) do { _Pragma("unroll")                            \
    for (int n = 0; n < 4; ++n)                                              \
        dst[n] = *(const short8*)(bL +                                       \
            (((buf)*2 + (ks))*16 + n) * 1024); } while (0)
#define MM16(bff, mh) do {                                                   \
    __builtin_amdgcn_s_setprio(1);                                           \
    _Pragma("unroll")                                                        \
    for (int m = 0; m < 4; ++m) { _Pragma("unroll")                          \
        for (int n = 0; n < 4; ++n)                                          \
            acc[(mh)*4 + m][n] = __builtin_amdgcn_mfma_f32_16x16x32_bf16(    \
                a_f[m], bff[n], acc[(mh)*4 + m][n], 0, 0, 0); }              \
    __builtin_amdgcn_s_setprio(0); } while (0)

#define TILE(buf, u) do {                                                    \
    LDA4(buf, 0, 0); LDB4(b_f0, buf, 0); STAGE_A(1-(buf), 1, (u)+1);         \
    BARRIER(); LGKM0(); MM16(b_f0, 0); BARRIER();                            \
    LDA4(buf, 0, 1); STAGE_B(1-(buf), 1, (u)+1);                             \
    BARRIER(); LGKM0(); MM16(b_f0, 1); BARRIER();                            \
    LDA4(buf, 1, 0); LDB4(b_f1, buf, 1); STAGE_A(buf, 0, (u)+2);             \
    BARRIER(); LGKM0(); MM16(b_f1, 0); BARRIER();                            \
    LDA4(buf, 1, 1); STAGE_B(buf, 0, (u)+2);                                 \
    BARRIER(); LGKM0(); MM16(b_f1, 1); VMCNT4(); BARRIER();                  \
} while (0)

    // ---- prologue: tile0 complete + tile1 Kh0; tile0 landed, Kh0(1) in flight
    STAGE_A(0, 0, 0); STAGE_B(0, 0, 0);
    STAGE_A(0, 1, 0); STAGE_B(0, 1, 0);
    STAGE_A(1, 0, 1); STAGE_B(1, 0, 1);
    VMCNT4(); BARRIER();

    // ---- main loop: 32 K-tiles, unrolled x2 for static buffer index ----
    for (int it = 0; it < NT2; it += 2) {
        TILE(0, it);
        TILE(1, it + 1);
    }

    // drain stray wrapped prefetches before reusing LDS
    VMCNT0();
    __syncthreads();

    // ---- fused epilogue: tanh + w_score partial over this col-tile ----
    float* part = (float*)smem;              // [4][256]
    const int fg = lane >> 4;
    float wsv[4], bsv[4];
    #pragma unroll
    for (int n = 0; n < 4; ++n) {
        int cg = c0 + wc * 64 + n * 16 + fr;
        wsv[n] = wscore[cg];
        bsv[n] = bias[cg];
    }
    #pragma unroll
    for (int mm = 0; mm < 8; ++mm) {
        #pragma unroll
        for (int r = 0; r < 4; ++r) {
            float s = 0.f;
            #pragma unroll
            for (int n = 0; n < 4; ++n)
                s += wsv[n] * fast_tanh(acc[mm][n][r] + bsv[n]);
            s += __shfl_xor(s, 1, 64);
            s += __shfl_xor(s, 2, 64);
            s += __shfl_xor(s, 4, 64);
            s += __shfl_xor(s, 8, 64);
            if (fr == 0)
                part[wc * 256 + wr * 128 + mm * 16 + fg * 4 + r] = s;
        }
    }
    __syncthreads();
    if (t < 256) {
        float v = part[t] + part[256 + t] + part[512 + t] + part[768 + t];
        spart[(size_t)(r0 + t) * 4 + bn] = v;
    }

#undef STAGE_A
#undef STAGE_B
#undef LDA4
#undef LDB4
#undef MM16
#undef TILE
}

// ---------------------------------------------------------------------------
// Kernel 3: per-batch softmax over L (sums the 4 partials in fixed order)
// ---------------------------------------------------------------------------
__global__ __launch_bounds__(256) void softmax_k(
    const float* __restrict__ spart,         // [M][4]
    float* __restrict__ attn)
{
    __shared__ float sc[L_SZ];
    __shared__ float red[8];
    const int b = blockIdx.x, t = threadIdx.x;
    const int lane = t & 63, wid = t >> 6;

    float lmax = -1e30f;
    #pragma unroll
    for (int i = 0; i < 8; ++i) {
        int l = t + i * 256;
        float4 u = *(const float4*)(spart + ((size_t)b * L_SZ + l) * 4);
        float s = (u.x + u.y) + (u.z + u.w);
        sc[l] = s;
        lmax = fmaxf(lmax, s);
    }
    #pragma unroll
    for (int off = 32; off; off >>= 1) lmax = fmaxf(lmax, __shfl_xor(lmax, off, 64));
    if (lane == 0) red[wid] = lmax;
    __syncthreads();
    float bmax = fmaxf(fmaxf(red[0], red[1]), fmaxf(red[2], red[3]));

    float lsum = 0.f;
    #pragma unroll
    for (int i = 0; i < 8; ++i) {
        int l = t + i * 256;
        float e = expf(sc[l] - bmax);
        sc[l] = e;
        lsum += e;
    }
    #pragma unroll
    for (int off = 32; off; off >>= 1) lsum += __shfl_xor(lsum, off, 64);
    if (lane == 0) red[4 + wid] = lsum;
    __syncthreads();
    float inv = 1.f / (((red[4] + red[5]) + (red[6] + red[7])));

    #pragma unroll
    for (int i = 0; i < 8; ++i) {
        int l = t + i * 256;
        attn[(size_t)b * L_SZ + l] = sc[l] * inv;
    }
}

// ---------------------------------------------------------------------------
// Kernel 4: context partials  cpart[b][lc][h] = sum_{l in chunk} attn*V
// ---------------------------------------------------------------------------
__global__ __launch_bounds__(256) void ctx_part_k(
    const float* __restrict__ attn, const float* __restrict__ value,
    float* __restrict__ cpart)
{
    const int bid = blockIdx.x;              // B*4*LC = 1024 blocks
    const int b   = bid >> 6;
    const int rem = bid & 63;
    const int hc  = rem >> 4;
    const int lc  = rem & 15;
    const int h   = hc * 256 + threadIdx.x;

    const float* ap = attn + (size_t)b * L_SZ + lc * LCHUNK;
    const float* vp = value + ((size_t)b * L_SZ + lc * LCHUNK) * H_SZ + h;
    float acc = 0.f;
    #pragma unroll 4
    for (int l = 0; l < LCHUNK; ++l)
        acc += ap[l] * vp[(size_t)l * H_SZ];
    cpart[((size_t)(b * LC + lc)) * H_SZ + h] = acc;
}

// ---------------------------------------------------------------------------
// Kernel 5: reduce context partials -> d_out[0:16384]
// ---------------------------------------------------------------------------
__global__ __launch_bounds__(256) void ctx_reduce_k(
    const float* __restrict__ cpart, float* __restrict__ ctx)
{
    const int idx = blockIdx.x * 256 + threadIdx.x;
    const int b = idx >> 10, h = idx & 1023;
    float s = 0.f;
    #pragma unroll
    for (int lc = 0; lc < LC; ++lc)
        s += cpart[((size_t)(b * LC + lc)) * H_SZ + h];
    ctx[idx] = s;
}

// ---------------------------------------------------------------------------
extern "C" void kernel_launch(void* const* d_in, const int* in_sizes, int n_in,
                              void* d_out, int out_size, void* d_ws, size_t ws_size,
                              hipStream_t stream) {
    const float* query  = (const float*)d_in[0];
    const float* key_t  = (const float*)d_in[1];
    const float* value  = (const float*)d_in[2];
    const float* Wq     = (const float*)d_in[3];
    const float* Wk     = (const float*)d_in[4];
    const float* bias   = (const float*)d_in[5];
    const float* wscore = (const float*)d_in[6];

    float* out      = (float*)d_out;
    float* ctx_out  = out;                    // [16][1024] context
    float* attn_out = out + B_SZ * H_SZ;      // [16][2048] attn

    char* ws = (char*)d_ws;                   // ws_size verified >= 140MB (fast path since R1)
    unsigned short* Wb = (unsigned short*)ws;                        // 4 MB
    float* spart = (float*)(ws + 4ull * 1024 * 1024);                // 512 KB [M][4]
    float* cpart = (float*)(ws + 5ull * 1024 * 1024);                // 1 MB
    unsigned short* Xb = (unsigned short*)(ws + 6ull * 1024 * 1024); // 128 MB

    // allow 128 KB dynamic LDS (idempotent; not a stream op)
    (void)hipFuncSetAttribute((const void*)score_gemm_8ph,
                              hipFuncAttributeMaxDynamicSharedMemorySize, 131072);

    int nblk = ((M_TOT + N_TOT) * KD / 8) / 256;                     // 33792
    concat_bf16<<<nblk, 256, 0, stream>>>(key_t, query, Wk, Wq, Xb, Wb);

    score_gemm_8ph<<<NBM2 * NBN2, 512, 131072, stream>>>(Xb, Wb, bias, wscore, spart);

    softmax_k<<<B_SZ, 256, 0, stream>>>(spart, attn_out);
    ctx_part_k<<<B_SZ * 4 * LC, 256, 0, stream>>>(attn_out, value, cpart);
    ctx_reduce_k<<<(B_SZ * H_SZ) / 256, 256, 0, stream>>>(cpart, ctx_out);
}

// Round 5
// 222.163 us; speedup vs baseline: 1.5333x; 1.0001x over previous
//
#include <hip/hip_runtime.h>
#include <hip/hip_bf16.h>
#include <math.h>

// Problem sizes
#define B_SZ 16
#define L_SZ 2048
#define H_SZ 1024
#define M_TOT (B_SZ * L_SZ)   // 32768 rows
#define N_TOT H_SZ            // 1024 outputs
#define KD (2 * H_SZ)         // 2048 concat K (key | query)
#define LC 16
#define LCHUNK (L_SZ / LC)    // 128

// 8-phase GEMM geometry (256^2 template)
#define BM2 256
#define BN2 256
#define BK2 64
#define NT2 (KD / BK2)        // 32 K-tiles
#define NBN2 (N_TOT / BN2)    // 4 col blocks
#define NBM2 (M_TOT / BM2)    // 128 row blocks

typedef short short8 __attribute__((ext_vector_type(8)));
typedef float f32x4 __attribute__((ext_vector_type(4)));

// ws layout: Wb @0 (4MB), spart @4MB (512KB), cpart @5MB (1MB), Xb @6MB (128MB)
#define WS_FAST_BYTES (6ull * 1024 * 1024 + 2ull * (size_t)M_TOT * KD)

#define GL16(gp, lp)                                                        \
    __builtin_amdgcn_global_load_lds(                                       \
        (const __attribute__((address_space(1))) unsigned int*)(gp),        \
        (__attribute__((address_space(3))) unsigned int*)(lp), 16, 0, 0)

#define BARRIER() __builtin_amdgcn_s_barrier()
// Plain asm waits — no sched_barrier(0) (m141: order-pinning −42%).
// vmcnt(8) is FIFO-exact: at each drain point exactly 8 newer gload_lds
// exist than the half-tile whose landing the next phase requires.
#define LGKM0()  asm volatile("s_waitcnt lgkmcnt(0)" ::: "memory")
#define VMCNT4() asm volatile("s_waitcnt vmcnt(4)" ::: "memory")
#define VMCNT8() asm volatile("s_waitcnt vmcnt(8)" ::: "memory")
#define VMCNT0() asm volatile("s_waitcnt vmcnt(0)" ::: "memory")

static __device__ __forceinline__ unsigned short f2bf(float f) {
    unsigned int u = __builtin_bit_cast(unsigned int, f);
    u += 0x7FFFu + ((u >> 16) & 1u);   // round-to-nearest-even
    return (unsigned short)(u >> 16);
}

static __device__ __forceinline__ short8 pack8(float4 x, float4 y) {
    short8 r;
    r[0] = (short)f2bf(x.x); r[1] = (short)f2bf(x.y);
    r[2] = (short)f2bf(x.z); r[3] = (short)f2bf(x.w);
    r[4] = (short)f2bf(y.x); r[5] = (short)f2bf(y.y);
    r[6] = (short)f2bf(y.z); r[7] = (short)f2bf(y.w);
    return r;
}

// tanh(x) = 1 - 2/(e^{2x}+1); v_exp_f32 + v_rcp_f32, ~1e-6 abs err,
// exact saturation at +-1.
static __device__ __forceinline__ float fast_tanh(float x) {
    float e = __expf(2.0f * x);
    return 1.0f - 2.0f * __builtin_amdgcn_rcpf(e + 1.0f);
}

// ---------------------------------------------------------------------------
// Kernel 1: concat + fp32->bf16.
// rows [0, 32768): Xb[row][0:1024]=key[row], [1024:2048]=query[row]
// rows [32768, 33792): Wb[o][0:1024]=Wk[o], [1024:2048]=Wq[o]
// ---------------------------------------------------------------------------
__global__ __launch_bounds__(256) void concat_bf16(
    const float* __restrict__ key, const float* __restrict__ query,
    const float* __restrict__ Wk, const float* __restrict__ Wq,
    unsigned short* __restrict__ Xb, unsigned short* __restrict__ Wb)
{
    long long e0 = ((long long)blockIdx.x * 256 + threadIdx.x) * 8;
    int row = (int)(e0 >> 11);
    int kk  = (int)(e0 & 2047);
    const float* a; const float* b; unsigned short* dst;
    if (row < M_TOT) { a = key; b = query; dst = Xb + e0; }
    else { row -= M_TOT; a = Wk; b = Wq; dst = Wb + (((long long)row << 11) | kk); }
    const float* src = (kk < H_SZ) ? (a + (size_t)row * H_SZ + kk)
                                   : (b + (size_t)row * H_SZ + (kk - H_SZ));
    float4 x = ((const float4*)src)[0];
    float4 y = ((const float4*)src)[1];
    *(short8*)dst = pack8(x, y);
}

// ---------------------------------------------------------------------------
// Kernel 2: 256x256x64 8-phase score GEMM (HK template re-derived).
//   LDS: A [2buf][2 khalf][16 rsub][1024B] @0, B same @64KB. st_16x32 swizzle
//   applied both-sides (pre-swizzled global source + swizzled ds_read addr).
//   Phases per K-tile: (ks0,mh0)+LDB0 | (ks0,mh1) | (ks1,mh0)+LDB1 | (ks1,mh1).
//   Stage stream in tile u: ph1 A-Kh1(u+1)->(1-buf).k1, ph2 B-Kh1(u+1),
//   ph3 A-Kh0(u+2)->buf.k0, ph4 B-Kh0(u+2).
//   Drains: vmcnt(8) at end-ph2 (guarantees Kh1(u) landed: 8 newer exist)
//   and vmcnt(8) at end-ph4 (guarantees Kh0(u+1) landed: 8 newer exist).
//   Each half-tile gets ~4 phases of flight >> HBM latency.
//   Fused epilogue: tanh + w_score partial reduction -> spart[M][4].
// ---------------------------------------------------------------------------
__global__ __launch_bounds__(512, 2) void score_gemm_8ph(
    const unsigned short* __restrict__ Xb,
    const unsigned short* __restrict__ Wb,
    const float* __restrict__ bias,
    const float* __restrict__ wscore,
    float* __restrict__ spart)               // [M][4]
{
    extern __shared__ char smem[];           // 128 KB dynamic
    char* Albase = smem;                     // A: 64 KB
    char* Blbase = smem + 65536;             // B: 64 KB

    const int t    = threadIdx.x;
    const int lane = t & 63;
    const int wid  = t >> 6;                 // 0..7
    const int wr   = wid >> 2;               // 0..1 (WARPS_M=2, 128 rows each)
    const int wc   = wid & 3;                // 0..3 (WARPS_N=4, 64 cols each)

    // XCD-aware remap: 512 blocks = 8 xcd * 16 bm * 4 bn (bn innermost)
    const int id  = blockIdx.x;
    const int xcd = id & 7;
    const int j   = id >> 3;                 // 0..63
    const int bn  = j & 3;
    const int bm  = xcd * 16 + (j >> 2);
    const int r0  = bm * BM2;
    const int c0  = bn * BN2;

    // ---- staging per-lane global offsets (pre-swizzled source) ----
    const int srow = lane >> 2;
    const int scol = ((lane & 3) * 8) ^ ((lane >= 32) ? 16 : 0);
    const size_t gA0 = (size_t)(r0 + (wid)     * 16 + srow) * KD + scol;
    const size_t gA1 = (size_t)(r0 + (8 + wid) * 16 + srow) * KD + scol;
    const size_t gB0 = (size_t)(c0 + (wid)     * 16 + srow) * KD + scol;
    const size_t gB1 = (size_t)(c0 + (8 + wid) * 16 + srow) * KD + scol;

    // ---- frag ds_read addressing (swizzled) ----
    const int fr  = lane & 15;               // row within subtile / C-col
    const int fk8 = (lane >> 4) * 8;         // k-offset within 32-k step
    const int subbyte = (fr * 64 + fk8 * 2) ^ ((fr & 8) << 2);  // ^32 if fr>=8
    const char* aL = Albase + wr * 8192 + subbyte;   // + rsub*1024 immediates
    const char* bL = Blbase + wc * 4096 + subbyte;

#define STAGE_A(buf, khalf, kt_) do {                                        \
    int kpos = (((kt_) & 31) * 64) + (khalf) * 32;                           \
    GL16(Xb + gA0 + kpos, Albase + (((buf)*2 + (khalf))*16 + wid)*1024);     \
    GL16(Xb + gA1 + kpos, Albase + (((buf)*2 + (khalf))*16 + 8 + wid)*1024); \
} while (0)
#define STAGE_B(buf, khalf, kt_) do {                                        \
    int kpos = (((kt_) & 31) * 64) + (khalf) * 32;                           \
    GL16(Wb + gB0 + kpos, Blbase + (((buf)*2 + (khalf))*16 + wid)*1024);     \
    GL16(Wb + gB1 + kpos, Blbase + (((buf)*2 + (khalf))*16 + 8 + wid)*1024); \
} while (0)

    short8 a_f[4], b_f0[4], b_f1[4];
    f32x4 acc[8][4] = {};

#define LDA4(buf, ks, mh) do { _Pragma("unroll")                             \
    for (int m = 0; m < 4; ++m)                                              \
        a_f[m] = *(const short8*)(aL +                                       \
            (((buf)*2 + (ks))*16 + (mh)*4 + m) * 1024); } while (0)
#define LDB4(dst, buf, ks) do { _Pragma("unroll")                            \
    for (int n = 0; n < 4; ++n)                                              \
        dst[n] = *(const short8*)(bL +                                       \
            (((buf)*2 + (ks))*16 + n) * 1024); } while (0)
#define MM16(bff, mh) do {                                                   \
    __builtin_amdgcn_s_setprio(1);                                           \
    _Pragma("unroll")                                                        \
    for (int m = 0; m < 4; ++m) { _Pragma("unroll")                          \
        for (int n = 0; n < 4; ++n)                                          \
            acc[(mh)*4 + m][n] = __builtin_amdgcn_mfma_f32_16x16x32_bf16(    \
                a_f[m], bff[n], acc[(mh)*4 + m][n], 0, 0, 0); }              \
    __builtin_amdgcn_s_setprio(0); } while (0)

#define TILE(buf, u) do {                                                    \
    LDA4(buf, 0, 0); LDB4(b_f0, buf, 0); STAGE_A(1-(buf), 1, (u)+1);         \
    BARRIER(); LGKM0(); MM16(b_f0, 0); BARRIER();                            \
    LDA4(buf, 0, 1); STAGE_B(1-(buf), 1, (u)+1);                             \
    BARRIER(); LGKM0(); MM16(b_f0, 1); VMCNT8(); BARRIER();                  \
    LDA4(buf, 1, 0); LDB4(b_f1, buf, 1); STAGE_A(buf, 0, (u)+2);             \
    BARRIER(); LGKM0(); MM16(b_f1, 0); BARRIER();                            \
    LDA4(buf, 1, 1); STAGE_B(buf, 0, (u)+2);                                 \
    BARRIER(); LGKM0(); MM16(b_f1, 1); VMCNT8(); BARRIER();                  \
} while (0)

    // ---- prologue: tile0 complete + tile1 Kh0; tile0 landed, Kh0(1) in flight
    STAGE_A(0, 0, 0); STAGE_B(0, 0, 0);
    STAGE_A(0, 1, 0); STAGE_B(0, 1, 0);
    STAGE_A(1, 0, 1); STAGE_B(1, 0, 1);
    VMCNT4(); BARRIER();

    // ---- main loop: 32 K-tiles, unrolled x2 for static buffer index ----
    for (int it = 0; it < NT2; it += 2) {
        TILE(0, it);
        TILE(1, it + 1);
    }

    // drain stray wrapped prefetches before reusing LDS
    VMCNT0();
    __syncthreads();

    // ---- fused epilogue: tanh + w_score partial over this col-tile ----
    float* part = (float*)smem;              // [4][256]
    const int fg = lane >> 4;
    float wsv[4], bsv[4];
    #pragma unroll
    for (int n = 0; n < 4; ++n) {
        int cg = c0 + wc * 64 + n * 16 + fr;
        wsv[n] = wscore[cg];
        bsv[n] = bias[cg];
    }
    #pragma unroll
    for (int mm = 0; mm < 8; ++mm) {
        #pragma unroll
        for (int r = 0; r < 4; ++r) {
            float s = 0.f;
            #pragma unroll
            for (int n = 0; n < 4; ++n)
                s += wsv[n] * fast_tanh(acc[mm][n][r] + bsv[n]);
            s += __shfl_xor(s, 1, 64);
            s += __shfl_xor(s, 2, 64);
            s += __shfl_xor(s, 4, 64);
            s += __shfl_xor(s, 8, 64);
            if (fr == 0)
                part[wc * 256 + wr * 128 + mm * 16 + fg * 4 + r] = s;
        }
    }
    __syncthreads();
    if (t < 256) {
        float v = part[t] + part[256 + t] + part[512 + t] + part[768 + t];
        spart[(size_t)(r0 + t) * 4 + bn] = v;
    }

#undef STAGE_A
#undef STAGE_B
#undef LDA4
#undef LDB4
#undef MM16
#undef TILE
}

// ---------------------------------------------------------------------------
// Kernel 3: per-batch softmax over L (sums the 4 partials in fixed order)
// ---------------------------------------------------------------------------
__global__ __launch_bounds__(256) void softmax_k(
    const float* __restrict__ spart,         // [M][4]
    float* __restrict__ attn)
{
    __shared__ float sc[L_SZ];
    __shared__ float red[8];
    const int b = blockIdx.x, t = threadIdx.x;
    const int lane = t & 63, wid = t >> 6;

    float lmax = -1e30f;
    #pragma unroll
    for (int i = 0; i < 8; ++i) {
        int l = t + i * 256;
        float4 u = *(const float4*)(spart + ((size_t)b * L_SZ + l) * 4);
        float s = (u.x + u.y) + (u.z + u.w);
        sc[l] = s;
        lmax = fmaxf(lmax, s);
    }
    #pragma unroll
    for (int off = 32; off; off >>= 1) lmax = fmaxf(lmax, __shfl_xor(lmax, off, 64));
    if (lane == 0) red[wid] = lmax;
    __syncthreads();
    float bmax = fmaxf(fmaxf(red[0], red[1]), fmaxf(red[2], red[3]));

    float lsum = 0.f;
    #pragma unroll
    for (int i = 0; i < 8; ++i) {
        int l = t + i * 256;
        float e = expf(sc[l] - bmax);
        sc[l] = e;
        lsum += e;
    }
    #pragma unroll
    for (int off = 32; off; off >>= 1) lsum += __shfl_xor(lsum, off, 64);
    if (lane == 0) red[4 + wid] = lsum;
    __syncthreads();
    float inv = 1.f / (((red[4] + red[5]) + (red[6] + red[7])));

    #pragma unroll
    for (int i = 0; i < 8; ++i) {
        int l = t + i * 256;
        attn[(size_t)b * L_SZ + l] = sc[l] * inv;
    }
}

// ---------------------------------------------------------------------------
// Kernel 4: context partials  cpart[b][lc][h] = sum_{l in chunk} attn*V
// ---------------------------------------------------------------------------
__global__ __launch_bounds__(256) void ctx_part_k(
    const float* __restrict__ attn, const float* __restrict__ value,
    float* __restrict__ cpart)
{
    const int bid = blockIdx.x;              // B*4*LC = 1024 blocks
    const int b   = bid >> 6;
    const int rem = bid & 63;
    const int hc  = rem >> 4;
    const int lc  = rem & 15;
    const int h   = hc * 256 + threadIdx.x;

    const float* ap = attn + (size_t)b * L_SZ + lc * LCHUNK;
    const float* vp = value + ((size_t)b * L_SZ + lc * LCHUNK) * H_SZ + h;
    float acc = 0.f;
    #pragma unroll 4
    for (int l = 0; l < LCHUNK; ++l)
        acc += ap[l] * vp[(size_t)l * H_SZ];
    cpart[((size_t)(b * LC + lc)) * H_SZ + h] = acc;
}

// ---------------------------------------------------------------------------
// Kernel 5: reduce context partials -> d_out[0:16384]
// ---------------------------------------------------------------------------
__global__ __launch_bounds__(256) void ctx_reduce_k(
    const float* __restrict__ cpart, float* __restrict__ ctx)
{
    const int idx = blockIdx.x * 256 + threadIdx.x;
    const int b = idx >> 10, h = idx & 1023;
    float s = 0.f;
    #pragma unroll
    for (int lc = 0; lc < LC; ++lc)
        s += cpart[((size_t)(b * LC + lc)) * H_SZ + h];
    ctx[idx] = s;
}

// ---------------------------------------------------------------------------
extern "C" void kernel_launch(void* const* d_in, const int* in_sizes, int n_in,
                              void* d_out, int out_size, void* d_ws, size_t ws_size,
                              hipStream_t stream) {
    const float* query  = (const float*)d_in[0];
    const float* key_t  = (const float*)d_in[1];
    const float* value  = (const float*)d_in[2];
    const float* Wq     = (const float*)d_in[3];
    const float* Wk     = (const float*)d_in[4];
    const float* bias   = (const float*)d_in[5];
    const float* wscore = (const float*)d_in[6];

    float* out      = (float*)d_out;
    float* ctx_out  = out;                    // [16][1024] context
    float* attn_out = out + B_SZ * H_SZ;      // [16][2048] attn

    char* ws = (char*)d_ws;                   // ws_size verified >= 140MB (fast path since R1)
    unsigned short* Wb = (unsigned short*)ws;                        // 4 MB
    float* spart = (float*)(ws + 4ull * 1024 * 1024);                // 512 KB [M][4]
    float* cpart = (float*)(ws + 5ull * 1024 * 1024);                // 1 MB
    unsigned short* Xb = (unsigned short*)(ws + 6ull * 1024 * 1024); // 128 MB

    // allow 128 KB dynamic LDS (idempotent; not a stream op)
    (void)hipFuncSetAttribute((const void*)score_gemm_8ph,
                              hipFuncAttributeMaxDynamicSharedMemorySize, 131072);

    int nblk = ((M_TOT + N_TOT) * KD / 8) / 256;                     // 33792
    concat_bf16<<<nblk, 256, 0, stream>>>(key_t, query, Wk, Wq, Xb, Wb);

    score_gemm_8ph<<<NBM2 * NBN2, 512, 131072, stream>>>(Xb, Wb, bias, wscore, spart);

    softmax_k<<<B_SZ, 256, 0, stream>>>(spart, attn_out);
    ctx_part_k<<<B_SZ * 4 * LC, 256, 0, stream>>>(attn_out, value, cpart);
    ctx_reduce_k<<<(B_SZ * H_SZ) / 256, 256, 0, stream>>>(cpart, ctx_out);
}